// Round 1
// baseline (1470.688 us; speedup 1.0000x reference)
//
#include <hip/hip_runtime.h>

#define TPB 256

// ---------------------------------------------------------------------------
// GCN: out = Linear( GCNConv2( ReLU(GCNConv1(x)) ) )
// GCNConv(x,W,b): h = x@W; hs = dinv * h; agg[d] = dinv[d]*(sum_{src->d} hs[src] + hs[d]) + b
// with deg[n] = 1 + indeg(n), dinv = rsqrt(deg).
// ---------------------------------------------------------------------------

__global__ void k_deg(const int* __restrict__ dst, float* __restrict__ deg, int E) {
    int e = blockIdx.x * TPB + threadIdx.x;
    if (e < E) atomicAdd(&deg[dst[e]], 1.0f);
}

__global__ void k_dinv(const float* __restrict__ deg, float* __restrict__ dinv, int N) {
    int n = blockIdx.x * TPB + threadIdx.x;
    if (n < N) dinv[n] = rsqrtf(deg[n] + 1.0f);   // +1 for self-loop
}

// hs[n][j] = dinv[n] * sum_k x[n][k] * W[k][j]   (16 -> 64)
__global__ void k_gemm1(const float* __restrict__ x, const float* __restrict__ W,
                        const float* __restrict__ dinv, float* __restrict__ hs, int N) {
    __shared__ float w[16 * 64];
    for (int i = threadIdx.x; i < 16 * 64; i += TPB) w[i] = W[i];
    __syncthreads();
    int gid = blockIdx.x * TPB + threadIdx.x;   // gid = n*64 + j
    int n = gid >> 6, j = gid & 63;
    if (n >= N) return;
    const float* xr = x + n * 16;               // wave-uniform row -> L1 broadcast
    float s = 0.f;
#pragma unroll
    for (int k = 0; k < 16; k++) s += xr[k] * w[k * 64 + j];
    hs[gid] = s * dinv[n];
}

// hs[n][j] = dinv[n] * sum_k h1[n][k] * W[k][j]  (64 -> 128)
__global__ void k_gemm2(const float* __restrict__ h1, const float* __restrict__ W,
                        const float* __restrict__ dinv, float* __restrict__ hs, int N) {
    __shared__ float w[64 * 128];                // 32 KiB
    for (int i = threadIdx.x; i < 64 * 128; i += TPB) w[i] = W[i];
    __syncthreads();
    int gid = blockIdx.x * TPB + threadIdx.x;   // gid = n*128 + j
    int n = gid >> 7, j = gid & 127;
    if (n >= N) return;
    const float* hr = h1 + n * 64;              // wave-uniform row
    float s = 0.f;
#pragma unroll
    for (int k = 0; k < 64; k++) s += hr[k] * w[k * 128 + j];
    hs[gid] = s * dinv[n];
}

// one thread per (edge, feature); wave = one edge's contiguous feature row
template <int F>
__global__ void k_scatter(const int* __restrict__ ei, const float* __restrict__ hs,
                          float* __restrict__ acc, int E) {
    int gid = blockIdx.x * TPB + threadIdx.x;
    int e = gid / F;                 // F is power of 2
    int f = gid & (F - 1);
    if (e >= E) return;
    int s = ei[e];                   // src
    int d = ei[E + e];               // dst
    atomicAdd(&acc[d * F + f], hs[s * F + f]);
}

// h1 = relu(dinv*(acc + hs) + b1), written in-place over acc
__global__ void k_act1(const float* __restrict__ hs, float* __restrict__ acc_h1,
                       const float* __restrict__ dinv, const float* __restrict__ b, int N) {
    int gid = blockIdx.x * TPB + threadIdx.x;
    if (gid >= N * 64) return;
    int n = gid >> 6, j = gid & 63;
    float v = dinv[n] * (acc_h1[gid] + hs[gid]) + b[j];
    acc_h1[gid] = v > 0.f ? v : 0.f;
}

// out[n][o] = bL[o] + sum_j (dinv[n]*(acc2+hs2)[n][j] + b2[j]) * WL[j][o]
__global__ void k_final(const float* __restrict__ hs2, const float* __restrict__ acc2,
                        const float* __restrict__ dinv, const float* __restrict__ b2,
                        const float* __restrict__ WL, const float* __restrict__ bL,
                        float* __restrict__ out, int N) {
    __shared__ float wl[128 * 16];
    __shared__ float sb2[128];
    __shared__ float sbL[16];
    int t = threadIdx.x;
    for (int i = t; i < 128 * 16; i += TPB) wl[i] = WL[i];
    if (t < 128) sb2[t] = b2[t];
    if (t < 16)  sbL[t] = bL[t];
    __syncthreads();
    int gid = blockIdx.x * TPB + t;              // gid = n*16 + o
    int n = gid >> 4, o = gid & 15;
    if (n >= N) return;
    const float4* A = (const float4*)(acc2 + (size_t)n * 128);
    const float4* H = (const float4*)(hs2 + (size_t)n * 128);
    float dn = dinv[n];
    float s = sbL[o];
#pragma unroll
    for (int q = 0; q < 32; q++) {
        float4 a = A[q];
        float4 h = H[q];
        float t0 = dn * (a.x + h.x) + sb2[4 * q + 0];
        float t1 = dn * (a.y + h.y) + sb2[4 * q + 1];
        float t2 = dn * (a.z + h.z) + sb2[4 * q + 2];
        float t3 = dn * (a.w + h.w) + sb2[4 * q + 3];
        s += t0 * wl[(4 * q + 0) * 16 + o];
        s += t1 * wl[(4 * q + 1) * 16 + o];
        s += t2 * wl[(4 * q + 2) * 16 + o];
        s += t3 * wl[(4 * q + 3) * 16 + o];
    }
    out[n * 16 + o] = s;
}

extern "C" void kernel_launch(void* const* d_in, const int* in_sizes, int n_in,
                              void* d_out, int out_size, void* d_ws, size_t ws_size,
                              hipStream_t stream) {
    const float* x  = (const float*)d_in[0];
    const int*   ei = (const int*)d_in[1];
    const float* W1 = (const float*)d_in[2];
    const float* b1 = (const float*)d_in[3];
    const float* W2 = (const float*)d_in[4];
    const float* b2 = (const float*)d_in[5];
    const float* WL = (const float*)d_in[6];
    const float* bL = (const float*)d_in[7];
    float* out = (float*)d_out;

    const int N = in_sizes[0] / 16;   // 100000
    const int E = in_sizes[1] / 2;    // 1600000

    // ws layout (floats): deg[N] | dinv[N] | buf0[N*128] | buf1[N*128]  (~103 MB)
    float* ws   = (float*)d_ws;
    float* deg  = ws;
    float* dinv = ws + N;
    float* buf0 = ws + (size_t)2 * N;                 // hs1 (64N) then hs2 (128N)
    float* buf1 = buf0 + (size_t)N * 128;             // acc1/h1 (64N) then acc2 (128N)

    // degrees
    hipMemsetAsync(deg, 0, (size_t)N * 4, stream);
    k_deg<<<(E + TPB - 1) / TPB, TPB, 0, stream>>>(ei + E, deg, E);
    k_dinv<<<(N + TPB - 1) / TPB, TPB, 0, stream>>>(deg, dinv, N);

    // ---- layer 1 (16 -> 64, relu) ----
    k_gemm1<<<((size_t)N * 64 + TPB - 1) / TPB, TPB, 0, stream>>>(x, W1, dinv, buf0, N);
    hipMemsetAsync(buf1, 0, (size_t)N * 64 * 4, stream);
    k_scatter<64><<<((size_t)E * 64 + TPB - 1) / TPB, TPB, 0, stream>>>(ei, buf0, buf1, E);
    k_act1<<<((size_t)N * 64 + TPB - 1) / TPB, TPB, 0, stream>>>(buf0, buf1, dinv, b1, N);
    // buf1 now holds h1 [N,64]

    // ---- layer 2 (64 -> 128) ----
    k_gemm2<<<((size_t)N * 128 + TPB - 1) / TPB, TPB, 0, stream>>>(buf1, W2, dinv, buf0, N);
    hipMemsetAsync(buf1, 0, (size_t)N * 128 * 4, stream);
    k_scatter<128><<<((size_t)E * 128 + TPB - 1) / TPB, TPB, 0, stream>>>(ei, buf0, buf1, E);

    // ---- fused bias + readout linear (128 -> 16) ----
    k_final<<<((size_t)N * 16 + TPB - 1) / TPB, TPB, 0, stream>>>(buf0, buf1, dinv, b2, WL, bL, out, N);
}

// Round 2
// 651.667 us; speedup vs baseline: 2.2568x; 2.2568x over previous
//
#include <hip/hip_runtime.h>

#define TPB 256

// ---------------------------------------------------------------------------
// GCN restructured via (A_norm)(h W) = (A_norm h) W:
//   hsx  = dinv * x                         [N,16]
//   aggx = hsx + scatter_sum(hsx[src]->dst) [N,16]   (self-loop folded via init)
//   hs1  = dinv * relu(dinv*aggx @ W1 + b1) [N,64]
//   acc1 = hs1 + scatter_sum(hs1[src]->dst) [N,64]
//   out  = dinv*acc1 @ (W2@WL) + (b2@WL + bL)        (conv2 + linear fused)
// ---------------------------------------------------------------------------

__global__ void k_deg(const int* __restrict__ dst, float* __restrict__ deg, int E) {
    int e = blockIdx.x * TPB + threadIdx.x;
    if (e < E) atomicAdd(&deg[dst[e]], 1.0f);
}

__global__ void k_dinv(const float* __restrict__ deg, float* __restrict__ dinv, int N) {
    int n = blockIdx.x * TPB + threadIdx.x;
    if (n < N) dinv[n] = rsqrtf(deg[n] + 1.0f);   // +1 for self-loop
}

// hsx = dinv*x, duplicated into the scatter accumulator (self-loop term)
__global__ void k_hsx(const float* __restrict__ x, const float* __restrict__ dinv,
                      float* __restrict__ hsx, float* __restrict__ acc, int N) {
    int gid = blockIdx.x * TPB + threadIdx.x;     // gid = n*16 + k
    if (gid >= N * 16) return;
    int n = gid >> 4;
    float v = dinv[n] * x[gid];
    hsx[gid] = v;
    acc[gid] = v;
}

// one thread per (edge, feature); wave covers contiguous feature rows
template <int F>
__global__ void k_scatter(const int* __restrict__ ei, const float* __restrict__ src_feat,
                          float* __restrict__ acc, int E) {
    int gid = blockIdx.x * TPB + threadIdx.x;
    int e = gid / F;
    int f = gid & (F - 1);
    if (e >= E) return;
    int s = ei[e];                   // src row
    int d = ei[E + e];               // dst row
    atomicAdd(&acc[d * F + f], src_feat[s * F + f]);
}

// hs1[n][j] = dinv[n] * relu(dinv[n] * (aggx[n] . W1[:,j]) + b1[j]); dup into acc1
__global__ void k_gemm1(const float* __restrict__ aggx, const float* __restrict__ W1,
                        const float* __restrict__ b1, const float* __restrict__ dinv,
                        float* __restrict__ hs1, float* __restrict__ acc1, int N) {
    __shared__ float w[16 * 64];
    __shared__ float sb[64];
    for (int i = threadIdx.x; i < 16 * 64; i += TPB) w[i] = W1[i];
    if (threadIdx.x < 64) sb[threadIdx.x] = b1[threadIdx.x];
    __syncthreads();
    int gid = blockIdx.x * TPB + threadIdx.x;     // gid = n*64 + j
    int n = gid >> 6, j = gid & 63;
    if (n >= N) return;
    const float* ar = aggx + n * 16;              // wave-uniform row
    float s = 0.f;
#pragma unroll
    for (int k = 0; k < 16; k++) s += ar[k] * w[k * 64 + j];
    float dn = dinv[n];
    float v = dn * s + sb[j];
    v = v > 0.f ? v : 0.f;
    v *= dn;
    hs1[gid] = v;
    acc1[gid] = v;
}

// Wf[k][o] = sum_j W2[k][j]*WL[j][o]  (64x16); bf[o] = sum_j b2[j]*WL[j][o] + bL[o]
__global__ void k_wfuse(const float* __restrict__ W2, const float* __restrict__ WL,
                        const float* __restrict__ b2, const float* __restrict__ bL,
                        float* __restrict__ Wf, float* __restrict__ bf) {
    int gid = blockIdx.x * TPB + threadIdx.x;     // 4 blocks * 256 = 1024 = 64*16
    int k = gid >> 4, o = gid & 15;
    if (k < 64) {
        float s = 0.f;
#pragma unroll 8
        for (int j = 0; j < 128; j++) s += W2[k * 128 + j] * WL[j * 16 + o];
        Wf[gid] = s;
    }
    if (gid < 16) {
        float s = bL[gid];
        for (int j = 0; j < 128; j++) s += b2[j] * WL[j * 16 + gid];
        bf[gid] = s;
    }
}

// out[n][o] = dinv[n] * (acc1[n] . Wf[:,o]) + bf[o]
__global__ void k_out(const float* __restrict__ acc1, const float* __restrict__ dinv,
                      const float* __restrict__ Wf, const float* __restrict__ bf,
                      float* __restrict__ out, int N) {
    __shared__ float wf[64 * 16];
    __shared__ float sbf[16];
    int t = threadIdx.x;
    for (int i = t; i < 64 * 16; i += TPB) wf[i] = Wf[i];
    if (t < 16) sbf[t] = bf[t];
    __syncthreads();
    int gid = blockIdx.x * TPB + t;               // gid = n*16 + o
    int n = gid >> 4, o = gid & 15;
    if (n >= N) return;
    const float4* A = (const float4*)(acc1 + (size_t)n * 64);
    float s = 0.f;
#pragma unroll
    for (int q = 0; q < 16; q++) {
        float4 a = A[q];
        s += a.x * wf[(4 * q + 0) * 16 + o];
        s += a.y * wf[(4 * q + 1) * 16 + o];
        s += a.z * wf[(4 * q + 2) * 16 + o];
        s += a.w * wf[(4 * q + 3) * 16 + o];
    }
    out[gid] = dinv[n] * s + sbf[o];
}

extern "C" void kernel_launch(void* const* d_in, const int* in_sizes, int n_in,
                              void* d_out, int out_size, void* d_ws, size_t ws_size,
                              hipStream_t stream) {
    const float* x  = (const float*)d_in[0];
    const int*   ei = (const int*)d_in[1];
    const float* W1 = (const float*)d_in[2];
    const float* b1 = (const float*)d_in[3];
    const float* W2 = (const float*)d_in[4];
    const float* b2 = (const float*)d_in[5];
    const float* WL = (const float*)d_in[6];
    const float* bL = (const float*)d_in[7];
    float* out = (float*)d_out;

    const int N = in_sizes[0] / 16;   // 100000
    const int E = in_sizes[1] / 2;    // 1600000

    // ws layout (floats): deg[N] dinv[N] hsx[16N] aggx[16N] hs1[64N] acc1[64N] Wf[1024] bf[16]
    float* ws   = (float*)d_ws;
    float* deg  = ws;
    float* dinv = ws + N;
    float* hsx  = dinv + N;
    float* aggx = hsx + (size_t)N * 16;
    float* hs1  = aggx + (size_t)N * 16;
    float* acc1 = hs1 + (size_t)N * 64;
    float* Wf   = acc1 + (size_t)N * 64;
    float* bf   = Wf + 64 * 16;

    // weight fusion (independent of node data — launch first)
    k_wfuse<<<4, TPB, 0, stream>>>(W2, WL, b2, bL, Wf, bf);

    // degrees
    hipMemsetAsync(deg, 0, (size_t)N * 4, stream);
    k_deg<<<(E + TPB - 1) / TPB, TPB, 0, stream>>>(ei + E, deg, E);
    k_dinv<<<(N + TPB - 1) / TPB, TPB, 0, stream>>>(deg, dinv, N);

    // ---- layer 1 aggregation at F=16 ----
    k_hsx<<<((size_t)N * 16 + TPB - 1) / TPB, TPB, 0, stream>>>(x, dinv, hsx, aggx, N);
    k_scatter<16><<<((size_t)E * 16 + TPB - 1) / TPB, TPB, 0, stream>>>(ei, hsx, aggx, E);

    // ---- GEMM 16->64 + relu + pre-scale, init acc1 with self-loop term ----
    k_gemm1<<<((size_t)N * 64 + TPB - 1) / TPB, TPB, 0, stream>>>(aggx, W1, b1, dinv, hs1, acc1, N);

    // ---- layer 2 aggregation at F=64 ----
    k_scatter<64><<<((size_t)E * 64 + TPB - 1) / TPB, TPB, 0, stream>>>(ei, hs1, acc1, E);

    // ---- fused conv2 + readout: out = dinv*acc1 @ Wf + bf ----
    k_out<<<((size_t)N * 16 + TPB - 1) / TPB, TPB, 0, stream>>>(acc1, dinv, Wf, bf, out, N);
}

// Round 3
// 542.490 us; speedup vs baseline: 2.7110x; 1.2013x over previous
//
#include <hip/hip_runtime.h>

#define TPB 256

// ---------------------------------------------------------------------------
// GCN via (A_norm)(h W) = (A_norm h) W, with CSR-gather aggregation:
//   deg/dinv; bucket[] = in-edge src lists per dst (unordered CSR via atomic alloc)
//   hsx  = dinv * x                          [N,16]
//   agg16[d] = hsx[d] + sum_{s in bucket(d)} hsx[s]
//   hs1  = dinv * relu(dinv * agg16 @ W1 + b1)   [N,64]
//   acc1[d] = hs1[d] + sum_{s in bucket(d)} hs1[s]
//   out  = dinv*acc1 @ (W2@WL) + (b2@WL + bL)
// ---------------------------------------------------------------------------

__global__ void k_deg(const int* __restrict__ dst, int* __restrict__ deg, int E) {
    int e = blockIdx.x * TPB + threadIdx.x;
    if (e < E) atomicAdd(&deg[dst[e]], 1);
}

// start[n] = alloc(deg[n]) — unordered CSR; cursor copy; dinv
__global__ void k_alloc(const int* __restrict__ deg, int* __restrict__ start,
                        int* __restrict__ cursor, float* __restrict__ dinv,
                        int* __restrict__ head, int N) {
    int n = blockIdx.x * TPB + threadIdx.x;
    if (n >= N) return;
    int d = deg[n];
    int s = atomicAdd(head, d);
    start[n] = s;
    cursor[n] = s;
    dinv[n] = rsqrtf((float)d + 1.0f);   // +1 self-loop
}

__global__ void k_bin(const int* __restrict__ ei, int* __restrict__ cursor,
                      int* __restrict__ bucket, int E) {
    int e = blockIdx.x * TPB + threadIdx.x;
    if (e >= E) return;
    int s = ei[e];
    int d = ei[E + e];
    int pos = atomicAdd(&cursor[d], 1);
    bucket[pos] = s;
}

__global__ void k_hsx(const float* __restrict__ x, const float* __restrict__ dinv,
                      float* __restrict__ hsx, int N) {
    int gid = blockIdx.x * TPB + threadIdx.x;     // gid = n*16 + k
    if (gid >= N * 16) return;
    hsx[gid] = dinv[gid >> 4] * x[gid];
}

// wave per node; lane = e_sub*16 + f; 4 edges per iteration, shfl reduction
__global__ void k_gather16(const int* __restrict__ bucket, const int* __restrict__ start,
                           const int* __restrict__ deg, const float* __restrict__ hsx,
                           float* __restrict__ agg, int N) {
    int gid = blockIdx.x * TPB + threadIdx.x;
    int n = gid >> 6;
    if (n >= N) return;
    int lane = threadIdx.x & 63;
    int es = lane >> 4, f = lane & 15;
    int base = start[n], d = deg[n];
    float sum = (es == 0) ? hsx[n * 16 + f] : 0.f;   // self-loop
    for (int k = es; k < d; k += 4) {
        int s = bucket[base + k];
        sum += hsx[s * 16 + f];
    }
    sum += __shfl_xor(sum, 16);
    sum += __shfl_xor(sum, 32);
    if (es == 0) agg[n * 16 + f] = sum;
}

// hs1[n][j] = dinv * relu(dinv * (agg16[n] . W1[:,j]) + b1[j])
__global__ void k_gemm1(const float* __restrict__ agg, const float* __restrict__ W1,
                        const float* __restrict__ b1, const float* __restrict__ dinv,
                        float* __restrict__ hs1, int N) {
    __shared__ float w[16 * 64];
    __shared__ float sb[64];
    for (int i = threadIdx.x; i < 16 * 64; i += TPB) w[i] = W1[i];
    if (threadIdx.x < 64) sb[threadIdx.x] = b1[threadIdx.x];
    __syncthreads();
    int gid = blockIdx.x * TPB + threadIdx.x;     // gid = n*64 + j
    int n = gid >> 6, j = gid & 63;
    if (n >= N) return;
    const float* ar = agg + n * 16;               // wave-uniform row
    float s = 0.f;
#pragma unroll
    for (int k = 0; k < 16; k++) s += ar[k] * w[k * 64 + j];
    float dn = dinv[n];
    float v = dn * s + sb[j];
    v = v > 0.f ? v : 0.f;
    hs1[gid] = v * dn;
}

// wave per node; lane = feature; sequential src list, coalesced 256B row gathers
__global__ void k_gather64(const int* __restrict__ bucket, const int* __restrict__ start,
                           const int* __restrict__ deg, const float* __restrict__ hs1,
                           float* __restrict__ acc, int N) {
    int gid = blockIdx.x * TPB + threadIdx.x;
    int n = gid >> 6;
    if (n >= N) return;
    int f = threadIdx.x & 63;
    int base = start[n], d = deg[n];
    float sum = hs1[n * 64 + f];                  // self-loop
    for (int k = 0; k < d; k++) {
        int s = bucket[base + k];                 // wave-uniform -> broadcast
        sum += hs1[s * 64 + f];
    }
    acc[n * 64 + f] = sum;
}

// Wf[k][o] = sum_j W2[k][j]*WL[j][o]; bf[o] = sum_j b2[j]*WL[j][o] + bL[o]
__global__ void k_wfuse(const float* __restrict__ W2, const float* __restrict__ WL,
                        const float* __restrict__ b2, const float* __restrict__ bL,
                        float* __restrict__ Wf, float* __restrict__ bf) {
    int gid = blockIdx.x * TPB + threadIdx.x;     // 4 blocks * 256 = 1024 = 64*16
    int k = gid >> 4, o = gid & 15;
    if (k < 64) {
        float s = 0.f;
#pragma unroll 8
        for (int j = 0; j < 128; j++) s += W2[k * 128 + j] * WL[j * 16 + o];
        Wf[gid] = s;
    }
    if (gid < 16) {
        float s = bL[gid];
        for (int j = 0; j < 128; j++) s += b2[j] * WL[j * 16 + gid];
        bf[gid] = s;
    }
}

// out[n][o] = dinv[n] * (acc1[n] . Wf[:,o]) + bf[o]
__global__ void k_out(const float* __restrict__ acc1, const float* __restrict__ dinv,
                      const float* __restrict__ Wf, const float* __restrict__ bf,
                      float* __restrict__ out, int N) {
    __shared__ float wf[64 * 16];
    __shared__ float sbf[16];
    int t = threadIdx.x;
    for (int i = t; i < 64 * 16; i += TPB) wf[i] = Wf[i];
    if (t < 16) sbf[t] = bf[t];
    __syncthreads();
    int gid = blockIdx.x * TPB + t;               // gid = n*16 + o
    int n = gid >> 4, o = gid & 15;
    if (n >= N) return;
    const float4* A = (const float4*)(acc1 + (size_t)n * 64);
    float s = 0.f;
#pragma unroll
    for (int q = 0; q < 16; q++) {
        float4 a = A[q];
        s += a.x * wf[(4 * q + 0) * 16 + o];
        s += a.y * wf[(4 * q + 1) * 16 + o];
        s += a.z * wf[(4 * q + 2) * 16 + o];
        s += a.w * wf[(4 * q + 3) * 16 + o];
    }
    out[gid] = dinv[n] * s + sbf[o];
}

extern "C" void kernel_launch(void* const* d_in, const int* in_sizes, int n_in,
                              void* d_out, int out_size, void* d_ws, size_t ws_size,
                              hipStream_t stream) {
    const float* x  = (const float*)d_in[0];
    const int*   ei = (const int*)d_in[1];
    const float* W1 = (const float*)d_in[2];
    const float* b1 = (const float*)d_in[3];
    const float* W2 = (const float*)d_in[4];
    const float* b2 = (const float*)d_in[5];
    const float* WL = (const float*)d_in[6];
    const float* bL = (const float*)d_in[7];
    float* out = (float*)d_out;

    const int N = in_sizes[0] / 16;   // 100000
    const int E = in_sizes[1] / 2;    // 1600000

    // ws layout: ints: deg[N] start[N] cursor[N] head[1] bucket[E]
    //            floats: dinv[N] hsx[16N] agg16[16N] hs1[64N] acc1[64N] Wf[1024] bf[16]
    int* wsi     = (int*)d_ws;
    int* deg     = wsi;
    int* start   = deg + N;
    int* cursor  = start + N;
    int* head    = cursor + N;
    int* bucket  = head + 1;
    float* dinv  = (float*)(bucket + E);
    float* hsx   = dinv + N;
    float* agg16 = hsx + (size_t)N * 16;
    float* hs1   = agg16 + (size_t)N * 16;
    float* acc1  = hs1 + (size_t)N * 64;
    float* Wf    = acc1 + (size_t)N * 64;
    float* bf    = Wf + 64 * 16;

    // weight fusion (independent — overlap with graph build)
    k_wfuse<<<4, TPB, 0, stream>>>(W2, WL, b2, bL, Wf, bf);

    // ---- CSR build ----
    hipMemsetAsync(deg, 0, (size_t)(N + 1) * 4 + (size_t)2 * N * 4, stream); // deg,start,cursor,head... (deg..head contiguous)
    k_deg<<<(E + TPB - 1) / TPB, TPB, 0, stream>>>(ei + E, deg, E);
    k_alloc<<<(N + TPB - 1) / TPB, TPB, 0, stream>>>(deg, start, cursor, dinv, head, N);
    k_bin<<<(E + TPB - 1) / TPB, TPB, 0, stream>>>(ei, cursor, bucket, E);

    // ---- layer 1 aggregation at F=16 ----
    k_hsx<<<((size_t)N * 16 + TPB - 1) / TPB, TPB, 0, stream>>>(x, dinv, hsx, N);
    k_gather16<<<((size_t)N * 64 + TPB - 1) / TPB, TPB, 0, stream>>>(bucket, start, deg, hsx, agg16, N);

    // ---- GEMM 16->64 + relu + pre-scale ----
    k_gemm1<<<((size_t)N * 64 + TPB - 1) / TPB, TPB, 0, stream>>>(agg16, W1, b1, dinv, hs1, N);

    // ---- layer 2 aggregation at F=64 ----
    k_gather64<<<((size_t)N * 64 + TPB - 1) / TPB, TPB, 0, stream>>>(bucket, start, deg, hs1, acc1, N);

    // ---- fused conv2 + readout ----
    k_out<<<((size_t)N * 16 + TPB - 1) / TPB, TPB, 0, stream>>>(acc1, dinv, Wf, bf, out, N);
}

// Round 4
// 450.222 us; speedup vs baseline: 3.2666x; 1.2049x over previous
//
#include <hip/hip_runtime.h>

#define TPB 256

// ---------------------------------------------------------------------------
// GCN via (A_norm)(h W) = (A_norm h) W, CSR-gather aggregation, MLP-optimized:
//   deg/dinv; bucket[] = in-edge src lists per dst (unordered CSR, atomic alloc)
//   hsx  = dinv * x                              [N,16]
//   agg16[d] = hsx[d] + sum_{s in bucket(d)} hsx[s]
//   hs1  = dinv * relu(dinv * agg16 @ W1 + b1)   [N,64]
//   acc1[d] = hs1[d] + sum_{s in bucket(d)} hs1[s]
//   out  = dinv*acc1 @ (W2@WL) + (b2@WL + bL)
// Gathers: wave per node, multiple edges in flight per wave (float4 rows).
// ---------------------------------------------------------------------------

__global__ void k_deg(const int* __restrict__ dst, int* __restrict__ deg, int E) {
    int e = blockIdx.x * TPB + threadIdx.x;
    if (e < E) atomicAdd(&deg[dst[e]], 1);
}

__global__ void k_alloc(const int* __restrict__ deg, int* __restrict__ start,
                        int* __restrict__ cursor, float* __restrict__ dinv,
                        int* __restrict__ head, int N) {
    int n = blockIdx.x * TPB + threadIdx.x;
    if (n >= N) return;
    int d = deg[n];
    int s = atomicAdd(head, d);
    start[n] = s;
    cursor[n] = s;
    dinv[n] = rsqrtf((float)d + 1.0f);   // +1 self-loop
}

__global__ void k_bin(const int* __restrict__ ei, int* __restrict__ cursor,
                      int* __restrict__ bucket, int E) {
    int e = blockIdx.x * TPB + threadIdx.x;
    if (e >= E) return;
    int s = ei[e];
    int d = ei[E + e];
    int pos = atomicAdd(&cursor[d], 1);
    bucket[pos] = s;
}

__global__ void k_hsx(const float* __restrict__ x, const float* __restrict__ dinv,
                      float* __restrict__ hsx, int N) {
    int gid = blockIdx.x * TPB + threadIdx.x;     // gid = n*16 + k
    if (gid >= N * 16) return;
    hsx[gid] = dinv[gid >> 4] * x[gid];
}

// wave per node; lane = g*4 + q: g in [0,16) = edge strand, q in [0,4) = float4 slot.
// 16 edges in flight per wave; rows are 64B = 4 float4.
__global__ void k_gather16(const int* __restrict__ bucket, const int* __restrict__ start,
                           const int* __restrict__ deg, const float4* __restrict__ hsx,
                           float4* __restrict__ agg, int N) {
    int n = (blockIdx.x * TPB + threadIdx.x) >> 6;
    if (n >= N) return;
    int lane = threadIdx.x & 63;
    int g = lane >> 2, q = lane & 3;
    int base = start[n], d = deg[n];
    float4 sum = make_float4(0.f, 0.f, 0.f, 0.f);
    if (g == 0) sum = hsx[n * 4 + q];             // self-loop
    for (int k = g; k < d; k += 16) {
        int s = bucket[base + k];
        float4 v = hsx[s * 4 + q];
        sum.x += v.x; sum.y += v.y; sum.z += v.z; sum.w += v.w;
    }
#pragma unroll
    for (int m = 4; m <= 32; m <<= 1) {
        sum.x += __shfl_xor(sum.x, m);
        sum.y += __shfl_xor(sum.y, m);
        sum.z += __shfl_xor(sum.z, m);
        sum.w += __shfl_xor(sum.w, m);
    }
    if (g == 0) agg[n * 4 + q] = sum;
}

// hs1[n][j] = dinv * relu(dinv * (agg16[n] . W1[:,j]) + b1[j])
__global__ void k_gemm1(const float* __restrict__ agg, const float* __restrict__ W1,
                        const float* __restrict__ b1, const float* __restrict__ dinv,
                        float* __restrict__ hs1, int N) {
    __shared__ float w[16 * 64];
    __shared__ float sb[64];
    for (int i = threadIdx.x; i < 16 * 64; i += TPB) w[i] = W1[i];
    if (threadIdx.x < 64) sb[threadIdx.x] = b1[threadIdx.x];
    __syncthreads();
    int gid = blockIdx.x * TPB + threadIdx.x;     // gid = n*64 + j
    int n = gid >> 6, j = gid & 63;
    if (n >= N) return;
    const float* ar = agg + n * 16;               // wave-uniform row
    float s = 0.f;
#pragma unroll
    for (int k = 0; k < 16; k++) s += ar[k] * w[k * 64 + j];
    float dn = dinv[n];
    float v = dn * s + sb[j];
    v = v > 0.f ? v : 0.f;
    hs1[gid] = v * dn;
}

// wave per node; lane = g*16 + q: g in [0,4) = edge strand, q in [0,16) = float4 slot.
// 2x unrolled -> 8 bucket->row chains in flight per wave; rows are 256B = 16 float4.
__global__ void k_gather64(const int* __restrict__ bucket, const int* __restrict__ start,
                           const int* __restrict__ deg, const float4* __restrict__ hs1,
                           float4* __restrict__ acc, int N) {
    int n = (blockIdx.x * TPB + threadIdx.x) >> 6;
    if (n >= N) return;
    int lane = threadIdx.x & 63;
    int g = lane >> 4, q = lane & 15;
    int base = start[n], d = deg[n];
    float4 sum = make_float4(0.f, 0.f, 0.f, 0.f);
    if (g == 0) sum = hs1[n * 16 + q];            // self-loop
    int k = g;
    for (; k + 4 < d; k += 8) {
        int s0 = bucket[base + k];
        int s1 = bucket[base + k + 4];
        float4 v0 = hs1[s0 * 16 + q];
        float4 v1 = hs1[s1 * 16 + q];
        sum.x += v0.x + v1.x; sum.y += v0.y + v1.y;
        sum.z += v0.z + v1.z; sum.w += v0.w + v1.w;
    }
    if (k < d) {
        int s = bucket[base + k];
        float4 v = hs1[s * 16 + q];
        sum.x += v.x; sum.y += v.y; sum.z += v.z; sum.w += v.w;
    }
#pragma unroll
    for (int m = 16; m <= 32; m <<= 1) {
        sum.x += __shfl_xor(sum.x, m);
        sum.y += __shfl_xor(sum.y, m);
        sum.z += __shfl_xor(sum.z, m);
        sum.w += __shfl_xor(sum.w, m);
    }
    if (g == 0) acc[n * 16 + q] = sum;
}

// Wf[k][o] = sum_j W2[k][j]*WL[j][o]; bf[o] = sum_j b2[j]*WL[j][o] + bL[o]
__global__ void k_wfuse(const float* __restrict__ W2, const float* __restrict__ WL,
                        const float* __restrict__ b2, const float* __restrict__ bL,
                        float* __restrict__ Wf, float* __restrict__ bf) {
    int gid = blockIdx.x * TPB + threadIdx.x;     // 4 blocks * 256 = 1024 = 64*16
    int k = gid >> 4, o = gid & 15;
    if (k < 64) {
        float s = 0.f;
#pragma unroll 8
        for (int j = 0; j < 128; j++) s += W2[k * 128 + j] * WL[j * 16 + o];
        Wf[gid] = s;
    }
    if (gid < 16) {
        float s = bL[gid];
        for (int j = 0; j < 128; j++) s += b2[j] * WL[j * 16 + gid];
        bf[gid] = s;
    }
}

// out[n][o] = dinv[n] * (acc1[n] . Wf[:,o]) + bf[o]
__global__ void k_out(const float* __restrict__ acc1, const float* __restrict__ dinv,
                      const float* __restrict__ Wf, const float* __restrict__ bf,
                      float* __restrict__ out, int N) {
    __shared__ float wf[64 * 16];
    __shared__ float sbf[16];
    int t = threadIdx.x;
    for (int i = t; i < 64 * 16; i += TPB) wf[i] = Wf[i];
    if (t < 16) sbf[t] = bf[t];
    __syncthreads();
    int gid = blockIdx.x * TPB + t;               // gid = n*16 + o
    int n = gid >> 4, o = gid & 15;
    if (n >= N) return;
    const float4* A = (const float4*)(acc1 + (size_t)n * 64);
    float s = 0.f;
#pragma unroll
    for (int q = 0; q < 16; q++) {
        float4 a = A[q];
        s += a.x * wf[(4 * q + 0) * 16 + o];
        s += a.y * wf[(4 * q + 1) * 16 + o];
        s += a.z * wf[(4 * q + 2) * 16 + o];
        s += a.w * wf[(4 * q + 3) * 16 + o];
    }
    out[gid] = dinv[n] * s + sbf[o];
}

extern "C" void kernel_launch(void* const* d_in, const int* in_sizes, int n_in,
                              void* d_out, int out_size, void* d_ws, size_t ws_size,
                              hipStream_t stream) {
    const float* x  = (const float*)d_in[0];
    const int*   ei = (const int*)d_in[1];
    const float* W1 = (const float*)d_in[2];
    const float* b1 = (const float*)d_in[3];
    const float* W2 = (const float*)d_in[4];
    const float* b2 = (const float*)d_in[5];
    const float* WL = (const float*)d_in[6];
    const float* bL = (const float*)d_in[7];
    float* out = (float*)d_out;

    const int N = in_sizes[0] / 16;   // 100000
    const int E = in_sizes[1] / 2;    // 1600000

    // ws layout: ints: deg[N] start[N] cursor[N] head[4-pad] bucket[E]
    //            floats (16B-aligned): dinv[N] hsx[16N] agg16[16N] hs1[64N] acc1[64N] Wf[1024] bf[16]
    int* wsi     = (int*)d_ws;
    int* deg     = wsi;
    int* start   = deg + N;
    int* cursor  = start + N;
    int* head    = cursor + N;                    // padded to 4 ints for alignment
    int* bucket  = head + 4;
    float* dinv  = (float*)(bucket + E);
    float* hsx   = dinv + N;
    float* agg16 = hsx + (size_t)N * 16;
    float* hs1   = agg16 + (size_t)N * 16;
    float* acc1  = hs1 + (size_t)N * 64;
    float* Wf    = acc1 + (size_t)N * 64;
    float* bf    = Wf + 64 * 16;

    // weight fusion (independent — overlap with graph build)
    k_wfuse<<<4, TPB, 0, stream>>>(W2, WL, b2, bL, Wf, bf);

    // ---- CSR build ----
    hipMemsetAsync(deg, 0, ((size_t)3 * N + 4) * 4, stream); // deg,start,cursor,head
    k_deg<<<(E + TPB - 1) / TPB, TPB, 0, stream>>>(ei + E, deg, E);
    k_alloc<<<(N + TPB - 1) / TPB, TPB, 0, stream>>>(deg, start, cursor, dinv, head, N);
    k_bin<<<(E + TPB - 1) / TPB, TPB, 0, stream>>>(ei, cursor, bucket, E);

    // ---- layer 1 aggregation at F=16 ----
    k_hsx<<<((size_t)N * 16 + TPB - 1) / TPB, TPB, 0, stream>>>(x, dinv, hsx, N);
    k_gather16<<<((size_t)N * 64 + TPB - 1) / TPB, TPB, 0, stream>>>(
        bucket, start, deg, (const float4*)hsx, (float4*)agg16, N);

    // ---- GEMM 16->64 + relu + pre-scale ----
    k_gemm1<<<((size_t)N * 64 + TPB - 1) / TPB, TPB, 0, stream>>>(agg16, W1, b1, dinv, hs1, N);

    // ---- layer 2 aggregation at F=64 ----
    k_gather64<<<((size_t)N * 64 + TPB - 1) / TPB, TPB, 0, stream>>>(
        bucket, start, deg, (const float4*)hs1, (float4*)acc1, N);

    // ---- fused conv2 + readout ----
    k_out<<<((size_t)N * 16 + TPB - 1) / TPB, TPB, 0, stream>>>(acc1, dinv, Wf, bf, out, N);
}